// Round 2
// baseline (821.999 us; speedup 1.0000x reference)
//
#include <hip/hip_runtime.h>
#include <cstdint>

typedef long long ll;
typedef unsigned long long ull;

constexpr int N_ = 1024;          // atoms (fixed by problem)
constexpr int BLK = 256;
constexpr int RNDS = 64;
constexpr int CHUNK = BLK * RNDS; // 16384 pairs per block

__device__ __forceinline__ ll rowstart(int i) {
  return (ll)i * (2 * N_ - 1 - i) / 2;
}

// invert triu(N,k=1) linear index -> (i,j)
__device__ __forceinline__ void decode_center(ll p, int& i, int& j) {
  double disc = (double)(2 * N_ - 1) * (double)(2 * N_ - 1) - 8.0 * (double)p;
  int ii = (int)(((double)(2 * N_ - 1) - sqrt(disc)) * 0.5);
  if (ii < 0) ii = 0;
  if (ii > N_ - 2) ii = N_ - 2;
  while (rowstart(ii) > p) --ii;
  while (rowstart(ii + 1) <= p) ++ii;
  i = ii;
  j = ii + 1 + (int)(p - rowstart(ii));
}

// ---------------- kernel 1: classify pairs -> bitmask, block counts, per-atom group counts
__global__ __launch_bounds__(BLK) void k_classify(
    const float* __restrict__ pos, const float* __restrict__ box,
    const int* __restrict__ shifts, int S, ll Pc, ll P,
    ull* __restrict__ mask64, unsigned* __restrict__ blockCount,
    unsigned* __restrict__ cntA, unsigned* __restrict__ cntB,
    unsigned* __restrict__ cntC, unsigned* __restrict__ cntD)
{
  __shared__ float4 sp[N_];
  __shared__ float ssv[16][3];
  __shared__ unsigned wcnt[4];
  int tid = threadIdx.x;
  for (int a = tid; a < N_; a += BLK)
    sp[a] = make_float4(pos[3 * a + 0], pos[3 * a + 1], pos[3 * a + 2], 0.f);
  if (tid < S) {
    for (int k = 0; k < 3; ++k) {
      float acc = 0.f;
      for (int m = 0; m < 3; ++m)
        acc = __fadd_rn(acc, __fmul_rn((float)shifts[3 * tid + m], box[3 * m + k]));
      ssv[tid][k] = acc;
    }
  }
  __syncthreads();
  int lane = tid & 63, wave = tid >> 6;
  ll chunk = (ll)blockIdx.x * CHUNK;
  unsigned wrun = 0;
  for (int r = 0; r < RNDS; ++r) {
    ll p0 = chunk + r * BLK + wave * 64;
    bool inr = (p0 < P);
    bool valid = false;
    if (inr) {
      ll p = p0 + lane;
      int i, j;
      float svx = 0.f, svy = 0.f, svz = 0.f;
      if (p < Pc) {
        decode_center(p, i, j);
      } else {
        ll q = p - Pc;
        int s = (int)(q >> 20);
        i = (int)((q >> 10) & (N_ - 1));
        j = (int)(q & (N_ - 1));
        svx = ssv[s][0]; svy = ssv[s][1]; svz = ssv[s][2];
      }
      float4 pi = sp[i], pj = sp[j];
      // strict IEEE order to match reference: (pi-pj)+sv, (x^2+y^2)+z^2, sqrt, <5
      float dx = __fadd_rn(__fsub_rn(pi.x, pj.x), svx);
      float dy = __fadd_rn(__fsub_rn(pi.y, pj.y), svy);
      float dz = __fadd_rn(__fsub_rn(pi.z, pj.z), svz);
      float d2 = __fadd_rn(__fadd_rn(__fmul_rn(dx, dx), __fmul_rn(dy, dy)),
                           __fmul_rn(dz, dz));
      valid = (sqrtf(d2) < 5.0f);
      if (valid) {
        if (p < Pc) { atomicAdd(&cntA[i], 1u); atomicAdd(&cntC[j], 1u); }
        else        { atomicAdd(&cntB[i], 1u); atomicAdd(&cntD[j], 1u); }
      }
    }
    ull bal = __ballot(valid);
    if (lane == 0) {
      if (inr) mask64[p0 >> 6] = bal;
      wrun += (unsigned)__popcll(bal);
    }
  }
  if (lane == 0) wcnt[wave] = wrun;
  __syncthreads();
  if (tid == 0)
    blockCount[blockIdx.x] = wcnt[0] + wcnt[1] + wcnt[2] + wcnt[3];
}

// ---------------- kernel 2: single-block scans -> blockOff, Vp/V, per-atom group bases
__global__ __launch_bounds__(1024) void k_scan(
    const unsigned* __restrict__ blockCount, unsigned* __restrict__ blockOff, int nb,
    const unsigned* __restrict__ cntA, const unsigned* __restrict__ cntB,
    const unsigned* __restrict__ cntC, const unsigned* __restrict__ cntD,
    unsigned* __restrict__ baseA, unsigned* __restrict__ baseB,
    unsigned* __restrict__ baseC, unsigned* __restrict__ baseD,
    unsigned* __restrict__ scal)
{
  __shared__ unsigned sm[1024];
  int t = threadIdx.x;
  unsigned v = (t < nb) ? blockCount[t] : 0u;
  sm[t] = v;
  for (int off = 1; off < 1024; off <<= 1) {
    __syncthreads();
    unsigned x = (t >= off) ? sm[t - off] : 0u;
    __syncthreads();
    sm[t] += x;
  }
  __syncthreads();
  if (t < nb) blockOff[t] = sm[t] - v;
  unsigned Vp = sm[1023];
  if (t == 0) { scal[0] = Vp; scal[1] = 2u * Vp; }
  __syncthreads();
  unsigned a4 = cntA[t], b4 = cntB[t], c4 = cntC[t], d4 = cntD[t];
  unsigned tot = a4 + b4 + c4 + d4;
  sm[t] = tot;
  for (int off = 1; off < 1024; off <<= 1) {
    __syncthreads();
    unsigned x = (t >= off) ? sm[t - off] : 0u;
    __syncthreads();
    sm[t] += x;
  }
  __syncthreads();
  unsigned excl = sm[t] - tot;
  baseA[t] = excl;
  baseB[t] = excl + a4;
  baseC[t] = excl + a4 + b4;
  baseD[t] = excl + a4 + b4 + c4;
}

// ---------------- kernel 3: scatter valid records (wave per (atom,group), stable ballot ranks)
__global__ __launch_bounds__(BLK) void k_valid(
    const ull* __restrict__ mask64, const float* __restrict__ box,
    const int* __restrict__ shifts, int S, ll Pc, ll T,
    const unsigned* __restrict__ baseA, const unsigned* __restrict__ baseB,
    const unsigned* __restrict__ baseC, const unsigned* __restrict__ baseD,
    float* __restrict__ out)
{
  __shared__ float ssv[16][3];
  int a = blockIdx.x;
  int tid = threadIdx.x, lane = tid & 63, wave = tid >> 6;
  if (tid < S) {
    for (int k = 0; k < 3; ++k) {
      float acc = 0.f;
      for (int m = 0; m < 3; ++m)
        acc = __fadd_rn(acc, __fmul_rn((float)shifts[3 * tid + m], box[3 * m + k]));
      ssv[tid][k] = acc;
    }
  }
  __syncthreads();
  float* oi = out;
  float* oj = out + T;
  float* oo = out + 2 * T;
  float* ov = out + 5 * T;
  ull lt = (1ull << lane) - 1ull;
  if (wave == 0) {                 // A: center forward, row (a, j>a), offset = 0
    unsigned run = baseA[a];
    int len = N_ - 1 - a;
    ll rb = rowstart(a);
    int steps = (len + 63) >> 6;
    for (int k = 0; k < steps; ++k) {
      int idx = (k << 6) + lane;
      bool v = false;
      if (idx < len) { ll b = rb + idx; v = (mask64[b >> 6] >> (b & 63)) & 1ull; }
      ull bal = __ballot(v);
      if (v) {
        ll pos = (ll)(run + (unsigned)__popcll(bal & lt));
        oi[pos] = (float)a; oj[pos] = (float)(a + 1 + idx); ov[pos] = 1.f;
        oo[3 * pos + 0] = 0.f; oo[3 * pos + 1] = 0.f; oo[3 * pos + 2] = 0.f;
      }
      run += (unsigned)__popcll(bal);
    }
  } else if (wave == 1) {          // B: shifted forward (s, a, j), offset = -sv[s]
    unsigned run = baseB[a];
    for (int s = 0; s < S; ++s) {
      ll bb = Pc + ((ll)s << 20) + ((ll)a << 10);
      float ox = -ssv[s][0], oy = -ssv[s][1], oz = -ssv[s][2];
      for (int k = 0; k < 16; ++k) {
        int j = (k << 6) + lane;
        ll b = bb + j;
        bool v = (mask64[b >> 6] >> (b & 63)) & 1ull;
        ull bal = __ballot(v);
        if (v) {
          ll pos = (ll)(run + (unsigned)__popcll(bal & lt));
          oi[pos] = (float)a; oj[pos] = (float)j; ov[pos] = 1.f;
          oo[3 * pos + 0] = ox; oo[3 * pos + 1] = oy; oo[3 * pos + 2] = oz;
        }
        run += (unsigned)__popcll(bal);
      }
    }
  } else if (wave == 2) {          // C: center reversed (i < a, a), offset = 0
    unsigned run = baseC[a];
    int steps = (a + 63) >> 6;
    for (int k = 0; k < steps; ++k) {
      int i = (k << 6) + lane;
      bool v = false;
      if (i < a) { ll b = rowstart(i) + (a - i - 1); v = (mask64[b >> 6] >> (b & 63)) & 1ull; }
      ull bal = __ballot(v);
      if (v) {
        ll pos = (ll)(run + (unsigned)__popcll(bal & lt));
        oi[pos] = (float)a; oj[pos] = (float)i; ov[pos] = 1.f;
        oo[3 * pos + 0] = 0.f; oo[3 * pos + 1] = 0.f; oo[3 * pos + 2] = 0.f;
      }
      run += (unsigned)__popcll(bal);
    }
  } else {                         // D: shifted reversed (s, i, a), offset = +sv[s]
    unsigned run = baseD[a];
    for (int s = 0; s < S; ++s) {
      ll bb = Pc + ((ll)s << 20) + a;
      float ox = ssv[s][0], oy = ssv[s][1], oz = ssv[s][2];
      for (int k = 0; k < 16; ++k) {
        int i = (k << 6) + lane;
        ll b = bb + ((ll)i << 10);
        bool v = (mask64[b >> 6] >> (b & 63)) & 1ull;
        ull bal = __ballot(v);
        if (v) {
          ll pos = (ll)(run + (unsigned)__popcll(bal & lt));
          oi[pos] = (float)a; oj[pos] = (float)i; ov[pos] = 1.f;
          oo[3 * pos + 0] = ox; oo[3 * pos + 1] = oy; oo[3 * pos + 2] = oz;
        }
        run += (unsigned)__popcll(bal);
      }
    }
  }
}

// ---------------- kernel 4: bulk invalid writer — writes idx, zero offset, zero valid
// for BOTH halves (forward + mirrored). Every invalid slot's bytes come from here;
// every valid slot's bytes come from k_valid. No runtime memset of d_out needed.
__global__ __launch_bounds__(BLK) void k_invalid(
    const ull* __restrict__ mask64, const unsigned* __restrict__ blockOff,
    const unsigned* __restrict__ scal, ll Pc, ll P, ll T,
    float* __restrict__ out)
{
  __shared__ unsigned wtot[4];
  int tid = threadIdx.x, lane = tid & 63, wave = tid >> 6;
  ll chunk = (ll)blockIdx.x * CHUNK;
  unsigned Vp = scal[0], V = scal[1];
  unsigned run = blockOff[blockIdx.x];
  ll invDelta = P - (ll)Vp;
  float* oi = out;
  float* oj = out + T;
  float* oo = out + 2 * T;
  float* ov = out + 5 * T;
  ull lt = (1ull << lane) - 1ull;
  for (int r = 0; r < RNDS; ++r) {
    ll p = chunk + (ll)r * BLK + tid;
    bool inr = (p < P);
    bool v = false;
    if (inr) v = (mask64[p >> 6] >> (p & 63)) & 1ull;
    ull bal = __ballot(v);
    if (lane == 0) wtot[wave] = (unsigned)__popcll(bal);
    __syncthreads();
    unsigned wexcl = 0, rtot = 0;
#pragma unroll
    for (int w2 = 0; w2 < 4; ++w2) {
      unsigned c = wtot[w2];
      if (w2 < wave) wexcl += c;
      rtot += c;
    }
    if (inr && !v) {
      unsigned pref = run + wexcl + (unsigned)__popcll(bal & lt);
      ll posF = (ll)V + (p - (ll)pref);   // # invalid before p, after valid region
      ll posR = posF + invDelta;          // mirrored second half
      int i, j;
      if (p < Pc) {
        decode_center(p, i, j);
      } else {
        ll q = p - Pc;
        i = (int)((q >> 10) & (N_ - 1));
        j = (int)(q & (N_ - 1));
      }
      float fi = (float)i, fj = (float)j;
      oi[posF] = fi; oj[posF] = fj;
      oo[3 * posF + 0] = 0.f; oo[3 * posF + 1] = 0.f; oo[3 * posF + 2] = 0.f;
      ov[posF] = 0.f;
      oi[posR] = fj; oj[posR] = fi;
      oo[3 * posR + 0] = 0.f; oo[3 * posR + 1] = 0.f; oo[3 * posR + 2] = 0.f;
      ov[posR] = 0.f;
    }
    run += rtot;
    __syncthreads();
  }
}

static inline unsigned char* alignup(unsigned char* p, size_t a) {
  return (unsigned char*)(((uintptr_t)p + a - 1) & ~(uintptr_t)(a - 1));
}

extern "C" void kernel_launch(void* const* d_in, const int* in_sizes, int n_in,
                              void* d_out, int out_size, void* d_ws, size_t ws_size,
                              hipStream_t stream)
{
  const float* pos = (const float*)d_in[0];
  const float* box = (const float*)d_in[1];
  const int* shifts = (const int*)d_in[2];
  int S = in_sizes[2] / 3;                       // 13
  ll Pc = (ll)N_ * (N_ - 1) / 2;                 // 523776
  ll P = Pc + (ll)S * N_ * N_;                   // 14,155,264
  ll T = 2 * P;                                  // 28,310,528
  float* out = (float*)d_out;
  int nb = (int)((P + CHUNK - 1) / CHUNK);       // 864

  unsigned char* w = (unsigned char*)d_ws;
  ull* mask64 = (ull*)w;
  w += ((P + 63) / 64) * sizeof(ull);
  w = alignup(w, 256);
  unsigned* blockCount = (unsigned*)w; w += (size_t)nb * 4;
  w = alignup(w, 256);
  unsigned* blockOff = (unsigned*)w;   w += (size_t)nb * 4;
  w = alignup(w, 256);
  unsigned* cnt = (unsigned*)w;        w += (size_t)4 * N_ * 4;  // A,B,C,D contiguous
  unsigned* cntA = cnt, *cntB = cnt + N_, *cntC = cnt + 2 * N_, *cntD = cnt + 3 * N_;
  unsigned* base = (unsigned*)w;       w += (size_t)4 * N_ * 4;
  unsigned* baseA = base, *baseB = base + N_, *baseC = base + 2 * N_, *baseD = base + 3 * N_;
  unsigned* scal = (unsigned*)w;       w += 64;

  // zero only the tiny atomic counters (16 KB); all of d_out is written by kernels
  hipMemsetAsync(cnt, 0, (size_t)4 * N_ * sizeof(unsigned), stream);

  k_classify<<<nb, BLK, 0, stream>>>(pos, box, shifts, S, Pc, P,
                                     mask64, blockCount, cntA, cntB, cntC, cntD);
  k_scan<<<1, 1024, 0, stream>>>(blockCount, blockOff, nb,
                                 cntA, cntB, cntC, cntD,
                                 baseA, baseB, baseC, baseD, scal);
  k_valid<<<N_, BLK, 0, stream>>>(mask64, box, shifts, S, Pc, T,
                                  baseA, baseB, baseC, baseD, out);
  k_invalid<<<nb, BLK, 0, stream>>>(mask64, blockOff, scal, Pc, P, T, out);
}

// Round 3
// 762.661 us; speedup vs baseline: 1.0778x; 1.0778x over previous
//
#include <hip/hip_runtime.h>
#include <cstdint>

typedef long long ll;
typedef unsigned long long ull;

constexpr int N_ = 1024;          // atoms (fixed by problem)
constexpr int BLK = 256;
constexpr int RNDS = 64;
constexpr int CHUNK = BLK * RNDS; // 16384 pairs per block
constexpr int QUART = CHUNK / 4;  // 4096 pairs per wave (64 mask words)

__device__ __forceinline__ ll rowstart(int i) {
  return (ll)i * (2 * N_ - 1 - i) / 2;
}

// invert triu(N,k=1) linear index -> (i,j)
__device__ __forceinline__ void decode_center(ll p, int& i, int& j) {
  double disc = (double)(2 * N_ - 1) * (double)(2 * N_ - 1) - 8.0 * (double)p;
  int ii = (int)(((double)(2 * N_ - 1) - sqrt(disc)) * 0.5);
  if (ii < 0) ii = 0;
  if (ii > N_ - 2) ii = N_ - 2;
  while (rowstart(ii) > p) --ii;
  while (rowstart(ii + 1) <= p) ++ii;
  i = ii;
  j = ii + 1 + (int)(p - rowstart(ii));
}

// ---------------- kernel 1: classify pairs -> bitmask, block counts, per-atom group counts
__global__ __launch_bounds__(BLK) void k_classify(
    const float* __restrict__ pos, const float* __restrict__ box,
    const int* __restrict__ shifts, int S, ll Pc, ll P,
    ull* __restrict__ mask64, unsigned* __restrict__ blockCount,
    unsigned* __restrict__ cntA, unsigned* __restrict__ cntB,
    unsigned* __restrict__ cntC, unsigned* __restrict__ cntD)
{
  __shared__ float4 sp[N_];
  __shared__ float ssv[16][3];
  __shared__ unsigned wcnt[4];
  int tid = threadIdx.x;
  for (int a = tid; a < N_; a += BLK)
    sp[a] = make_float4(pos[3 * a + 0], pos[3 * a + 1], pos[3 * a + 2], 0.f);
  if (tid < S) {
    for (int k = 0; k < 3; ++k) {
      float acc = 0.f;
      for (int m = 0; m < 3; ++m)
        acc = __fadd_rn(acc, __fmul_rn((float)shifts[3 * tid + m], box[3 * m + k]));
      ssv[tid][k] = acc;
    }
  }
  __syncthreads();
  int lane = tid & 63, wave = tid >> 6;
  ll chunk = (ll)blockIdx.x * CHUNK;
  unsigned wrun = 0;
  for (int r = 0; r < RNDS; ++r) {
    ll p0 = chunk + r * BLK + wave * 64;
    bool inr = (p0 < P);
    bool valid = false;
    if (inr) {
      ll p = p0 + lane;
      int i, j;
      float svx = 0.f, svy = 0.f, svz = 0.f;
      if (p < Pc) {
        decode_center(p, i, j);
      } else {
        ll q = p - Pc;
        int s = (int)(q >> 20);
        i = (int)((q >> 10) & (N_ - 1));
        j = (int)(q & (N_ - 1));
        svx = ssv[s][0]; svy = ssv[s][1]; svz = ssv[s][2];
      }
      float4 pi = sp[i], pj = sp[j];
      // strict IEEE order to match reference: (pi-pj)+sv, (x^2+y^2)+z^2, sqrt, <5
      float dx = __fadd_rn(__fsub_rn(pi.x, pj.x), svx);
      float dy = __fadd_rn(__fsub_rn(pi.y, pj.y), svy);
      float dz = __fadd_rn(__fsub_rn(pi.z, pj.z), svz);
      float d2 = __fadd_rn(__fadd_rn(__fmul_rn(dx, dx), __fmul_rn(dy, dy)),
                           __fmul_rn(dz, dz));
      valid = (sqrtf(d2) < 5.0f);
      if (valid) {
        if (p < Pc) { atomicAdd(&cntA[i], 1u); atomicAdd(&cntC[j], 1u); }
        else        { atomicAdd(&cntB[i], 1u); atomicAdd(&cntD[j], 1u); }
      }
    }
    ull bal = __ballot(valid);
    if (lane == 0) {
      if (inr) mask64[p0 >> 6] = bal;
      wrun += (unsigned)__popcll(bal);
    }
  }
  if (lane == 0) wcnt[wave] = wrun;
  __syncthreads();
  if (tid == 0)
    blockCount[blockIdx.x] = wcnt[0] + wcnt[1] + wcnt[2] + wcnt[3];
}

// ---------------- kernel 2: single-block scans -> blockOff, Vp/V, per-atom group bases
__global__ __launch_bounds__(1024) void k_scan(
    const unsigned* __restrict__ blockCount, unsigned* __restrict__ blockOff, int nb,
    const unsigned* __restrict__ cntA, const unsigned* __restrict__ cntB,
    const unsigned* __restrict__ cntC, const unsigned* __restrict__ cntD,
    unsigned* __restrict__ baseA, unsigned* __restrict__ baseB,
    unsigned* __restrict__ baseC, unsigned* __restrict__ baseD,
    unsigned* __restrict__ scal)
{
  __shared__ unsigned sm[1024];
  int t = threadIdx.x;
  unsigned v = (t < nb) ? blockCount[t] : 0u;
  sm[t] = v;
  for (int off = 1; off < 1024; off <<= 1) {
    __syncthreads();
    unsigned x = (t >= off) ? sm[t - off] : 0u;
    __syncthreads();
    sm[t] += x;
  }
  __syncthreads();
  if (t < nb) blockOff[t] = sm[t] - v;
  unsigned Vp = sm[1023];
  if (t == 0) { scal[0] = Vp; scal[1] = 2u * Vp; }
  __syncthreads();
  unsigned a4 = cntA[t], b4 = cntB[t], c4 = cntC[t], d4 = cntD[t];
  unsigned tot = a4 + b4 + c4 + d4;
  sm[t] = tot;
  for (int off = 1; off < 1024; off <<= 1) {
    __syncthreads();
    unsigned x = (t >= off) ? sm[t - off] : 0u;
    __syncthreads();
    sm[t] += x;
  }
  __syncthreads();
  unsigned excl = sm[t] - tot;
  baseA[t] = excl;
  baseB[t] = excl + a4;
  baseC[t] = excl + a4 + b4;
  baseD[t] = excl + a4 + b4 + c4;
}

// ---------------- kernel 3: scatter valid records (wave per (atom,group), stable ballot ranks)
// offsets for center groups (A/C) and valid flags' zero default come from the memset.
__global__ __launch_bounds__(BLK) void k_valid(
    const ull* __restrict__ mask64, const float* __restrict__ box,
    const int* __restrict__ shifts, int S, ll Pc, ll T,
    const unsigned* __restrict__ baseA, const unsigned* __restrict__ baseB,
    const unsigned* __restrict__ baseC, const unsigned* __restrict__ baseD,
    float* __restrict__ out)
{
  __shared__ float ssv[16][3];
  int a = blockIdx.x;
  int tid = threadIdx.x, lane = tid & 63, wave = tid >> 6;
  if (tid < S) {
    for (int k = 0; k < 3; ++k) {
      float acc = 0.f;
      for (int m = 0; m < 3; ++m)
        acc = __fadd_rn(acc, __fmul_rn((float)shifts[3 * tid + m], box[3 * m + k]));
      ssv[tid][k] = acc;
    }
  }
  __syncthreads();
  float* oi = out;
  float* oj = out + T;
  float* oo = out + 2 * T;
  float* ov = out + 5 * T;
  ull lt = (1ull << lane) - 1ull;
  if (wave == 0) {                 // A: center forward, row (a, j>a), offset = 0 (memset)
    unsigned run = baseA[a];
    int len = N_ - 1 - a;
    ll rb = rowstart(a);
    int steps = (len + 63) >> 6;
    for (int k = 0; k < steps; ++k) {
      int idx = (k << 6) + lane;
      bool v = false;
      if (idx < len) { ll b = rb + idx; v = (mask64[b >> 6] >> (b & 63)) & 1ull; }
      ull bal = __ballot(v);
      if (v) {
        ll pos = (ll)(run + (unsigned)__popcll(bal & lt));
        oi[pos] = (float)a; oj[pos] = (float)(a + 1 + idx); ov[pos] = 1.f;
      }
      run += (unsigned)__popcll(bal);
    }
  } else if (wave == 1) {          // B: shifted forward (s, a, j), offset = -sv[s]
    unsigned run = baseB[a];
    for (int s = 0; s < S; ++s) {
      ll bb = Pc + ((ll)s << 20) + ((ll)a << 10);
      float ox = -ssv[s][0], oy = -ssv[s][1], oz = -ssv[s][2];
      for (int k = 0; k < 16; ++k) {
        int j = (k << 6) + lane;
        ll b = bb + j;
        bool v = (mask64[b >> 6] >> (b & 63)) & 1ull;
        ull bal = __ballot(v);
        if (v) {
          ll pos = (ll)(run + (unsigned)__popcll(bal & lt));
          oi[pos] = (float)a; oj[pos] = (float)j; ov[pos] = 1.f;
          oo[3 * pos + 0] = ox; oo[3 * pos + 1] = oy; oo[3 * pos + 2] = oz;
        }
        run += (unsigned)__popcll(bal);
      }
    }
  } else if (wave == 2) {          // C: center reversed (i < a, a), offset = 0 (memset)
    unsigned run = baseC[a];
    int steps = (a + 63) >> 6;
    for (int k = 0; k < steps; ++k) {
      int i = (k << 6) + lane;
      bool v = false;
      if (i < a) { ll b = rowstart(i) + (a - i - 1); v = (mask64[b >> 6] >> (b & 63)) & 1ull; }
      ull bal = __ballot(v);
      if (v) {
        ll pos = (ll)(run + (unsigned)__popcll(bal & lt));
        oi[pos] = (float)a; oj[pos] = (float)i; ov[pos] = 1.f;
      }
      run += (unsigned)__popcll(bal);
    }
  } else {                         // D: shifted reversed (s, i, a), offset = +sv[s]
    unsigned run = baseD[a];
    for (int s = 0; s < S; ++s) {
      ll bb = Pc + ((ll)s << 20) + a;
      float ox = ssv[s][0], oy = ssv[s][1], oz = ssv[s][2];
      for (int k = 0; k < 16; ++k) {
        int i = (k << 6) + lane;
        ll b = bb + ((ll)i << 10);
        bool v = (mask64[b >> 6] >> (b & 63)) & 1ull;
        ull bal = __ballot(v);
        if (v) {
          ll pos = (ll)(run + (unsigned)__popcll(bal & lt));
          oi[pos] = (float)a; oj[pos] = (float)i; ov[pos] = 1.f;
          oo[3 * pos + 0] = ox; oo[3 * pos + 1] = oy; oo[3 * pos + 2] = oz;
        }
        run += (unsigned)__popcll(bal);
      }
    }
  }
}

// ---------------- kernel 4: bulk invalid idx writer.
// Each wave owns a contiguous 4096-pair quarter = 64 mask words = 1 word/lane in
// register; per-iteration word broadcast via __shfl. No barriers in the main loop.
__global__ __launch_bounds__(BLK) void k_invalid(
    const ull* __restrict__ mask64, const unsigned* __restrict__ blockOff,
    const unsigned* __restrict__ scal, ll Pc, ll P, ll T,
    float* __restrict__ out)
{
  __shared__ unsigned wq[4];
  int tid = threadIdx.x, lane = tid & 63, wave = tid >> 6;
  ll Wtot = P >> 6;
  ll qbase = (ll)blockIdx.x * CHUNK + (ll)wave * QUART;
  ll widx = (qbase >> 6) + lane;
  ull myword = (widx < Wtot) ? mask64[widx] : ~0ull;   // OOB words: "all valid" -> no writes
  // wave-wide valid count of this quarter
  unsigned ws = (unsigned)__popcll(myword);
  for (int d = 1; d < 64; d <<= 1) ws += __shfl_xor(ws, d);
  if (lane == 0) wq[wave] = ws;
  __syncthreads();
  unsigned gv = blockOff[blockIdx.x];                  // global valid count before this block
  for (int w2 = 0; w2 < 4; ++w2) if (w2 < wave) gv += wq[w2];
  unsigned Vp = scal[0], V = scal[1];
  ll invDelta = P - (ll)Vp;
  float* oi = out;
  float* oj = out + T;
  ull lt = (1ull << lane) - 1ull;
  unsigned vrun = gv;                                  // valid count before current word
  for (int k = 0; k < 64; ++k) {
    ull w64 = __shfl((long long)myword, k);
    ll p = qbase + (k << 6) + lane;
    bool invalid = !((w64 >> lane) & 1ull) && (p < P);
    if (invalid) {
      unsigned vb = vrun + (unsigned)__popcll(w64 & lt);
      ll posF = (ll)V + (p - (ll)vb);
      ll posR = posF + invDelta;
      int i, j;
      if (p < Pc) {
        decode_center(p, i, j);
      } else {
        ll q = p - Pc;
        i = (int)((q >> 10) & (N_ - 1));
        j = (int)(q & (N_ - 1));
      }
      float fi = (float)i, fj = (float)j;
      oi[posF] = fi; oj[posF] = fj;
      oi[posR] = fj; oj[posR] = fi;
    }
    vrun += (unsigned)__popcll(w64);
  }
}

static inline unsigned char* alignup(unsigned char* p, size_t a) {
  return (unsigned char*)(((uintptr_t)p + a - 1) & ~(uintptr_t)(a - 1));
}

extern "C" void kernel_launch(void* const* d_in, const int* in_sizes, int n_in,
                              void* d_out, int out_size, void* d_ws, size_t ws_size,
                              hipStream_t stream)
{
  const float* pos = (const float*)d_in[0];
  const float* box = (const float*)d_in[1];
  const int* shifts = (const int*)d_in[2];
  int S = in_sizes[2] / 3;                       // 13
  ll Pc = (ll)N_ * (N_ - 1) / 2;                 // 523776
  ll P = Pc + (ll)S * N_ * N_;                   // 14,155,264
  ll T = 2 * P;                                  // 28,310,528
  float* out = (float*)d_out;
  int nb = (int)((P + CHUNK - 1) / CHUNK);       // 864

  unsigned char* w = (unsigned char*)d_ws;
  ull* mask64 = (ull*)w;
  w += ((P + 63) / 64) * sizeof(ull);
  w = alignup(w, 256);
  unsigned* blockCount = (unsigned*)w; w += (size_t)nb * 4;
  w = alignup(w, 256);
  unsigned* blockOff = (unsigned*)w;   w += (size_t)nb * 4;
  w = alignup(w, 256);
  unsigned* cnt = (unsigned*)w;        w += (size_t)4 * N_ * 4;  // A,B,C,D contiguous
  unsigned* cntA = cnt, *cntB = cnt + N_, *cntC = cnt + 2 * N_, *cntD = cnt + 3 * N_;
  unsigned* base = (unsigned*)w;       w += (size_t)4 * N_ * 4;
  unsigned* baseA = base, *baseB = base + N_, *baseC = base + 2 * N_, *baseD = base + 3 * N_;
  unsigned* scal = (unsigned*)w;       w += 64;

  // zero atomic counters (16 KB) and the offset+valid output regions [2T,6T) —
  // a contiguous 453 MB fill at rocclr-fill speed (~6.2 TB/s); invalid slots'
  // offset/valid stay zero, k_valid overwrites only the ~40K valid slots.
  hipMemsetAsync(cnt, 0, (size_t)4 * N_ * sizeof(unsigned), stream);
  hipMemsetAsync(out + 2 * T, 0, (size_t)(4 * T) * sizeof(float), stream);

  k_classify<<<nb, BLK, 0, stream>>>(pos, box, shifts, S, Pc, P,
                                     mask64, blockCount, cntA, cntB, cntC, cntD);
  k_scan<<<1, 1024, 0, stream>>>(blockCount, blockOff, nb,
                                 cntA, cntB, cntC, cntD,
                                 baseA, baseB, baseC, baseD, scal);
  k_valid<<<N_, BLK, 0, stream>>>(mask64, box, shifts, S, Pc, T,
                                  baseA, baseB, baseC, baseD, out);
  k_invalid<<<nb, BLK, 0, stream>>>(mask64, blockOff, scal, Pc, P, T, out);
}

// Round 4
// 731.007 us; speedup vs baseline: 1.1245x; 1.0433x over previous
//
#include <hip/hip_runtime.h>
#include <cstdint>

typedef long long ll;
typedef unsigned long long ull;

constexpr int N_ = 1024;          // atoms (fixed by problem)
constexpr int BLK = 256;
constexpr int RNDS = 64;
constexpr int CHUNK = BLK * RNDS; // 16384 pairs per block
constexpr int QUART = CHUNK / 4;  // 4096 pairs per wave (64 mask words)
constexpr int F4PB = 32768;       // float4 zero-fill quota per classify block

__device__ __forceinline__ ll rowstart(int i) {
  return (ll)i * (2 * N_ - 1 - i) / 2;
}

// invert triu(N,k=1) linear index -> (i,j)
__device__ __forceinline__ void decode_center(ll p, int& i, int& j) {
  double disc = (double)(2 * N_ - 1) * (double)(2 * N_ - 1) - 8.0 * (double)p;
  int ii = (int)(((double)(2 * N_ - 1) - sqrt(disc)) * 0.5);
  if (ii < 0) ii = 0;
  if (ii > N_ - 2) ii = N_ - 2;
  while (rowstart(ii) > p) --ii;
  while (rowstart(ii + 1) <= p) ++ii;
  i = ii;
  j = ii + 1 + (int)(p - rowstart(ii));
}

// ---------------- kernel 1: classify pairs -> bitmask + counts, FUSED zero-fill of
// out[2T,6T) (offset+valid regions) as contiguous float4 streams overlapping the
// VALU classify work (replaces the serial 453 MB memset stage).
__global__ __launch_bounds__(BLK) void k_classify(
    const float* __restrict__ pos, const float* __restrict__ box,
    const int* __restrict__ shifts, int S, ll Pc, ll P, ll T4,
    float4* __restrict__ zp,
    ull* __restrict__ mask64, unsigned* __restrict__ blockCount,
    unsigned* __restrict__ cntA, unsigned* __restrict__ cntB,
    unsigned* __restrict__ cntC, unsigned* __restrict__ cntD)
{
  __shared__ float4 sp[N_];
  __shared__ float ssv[16][3];
  __shared__ unsigned wcnt[4];
  int tid = threadIdx.x;
  for (int a = tid; a < N_; a += BLK)
    sp[a] = make_float4(pos[3 * a + 0], pos[3 * a + 1], pos[3 * a + 2], 0.f);
  if (tid < S) {
    for (int k = 0; k < 3; ++k) {
      float acc = 0.f;
      for (int m = 0; m < 3; ++m)
        acc = __fadd_rn(acc, __fmul_rn((float)shifts[3 * tid + m], box[3 * m + k]));
      ssv[tid][k] = acc;
    }
  }
  __syncthreads();
  int lane = tid & 63, wave = tid >> 6;
  ll chunk = (ll)blockIdx.x * CHUNK;
  ll fillBase = (ll)blockIdx.x * F4PB + tid;
  const float4 z4 = make_float4(0.f, 0.f, 0.f, 0.f);
  unsigned wrun = 0;
  for (int r = 0; r < RNDS; ++r) {
    ll p0 = chunk + r * BLK + wave * 64;
    bool inr = (p0 < P);
    bool valid = false;
    if (inr) {
      ll p = p0 + lane;
      int i, j;
      float svx = 0.f, svy = 0.f, svz = 0.f;
      if (p < Pc) {
        decode_center(p, i, j);
      } else {
        ll q = p - Pc;
        int s = (int)(q >> 20);
        i = (int)((q >> 10) & (N_ - 1));
        j = (int)(q & (N_ - 1));
        svx = ssv[s][0]; svy = ssv[s][1]; svz = ssv[s][2];
      }
      float4 pi = sp[i], pj = sp[j];
      // strict IEEE order to match reference: (pi-pj)+sv, (x^2+y^2)+z^2, sqrt, <5
      float dx = __fadd_rn(__fsub_rn(pi.x, pj.x), svx);
      float dy = __fadd_rn(__fsub_rn(pi.y, pj.y), svy);
      float dz = __fadd_rn(__fsub_rn(pi.z, pj.z), svz);
      float d2 = __fadd_rn(__fadd_rn(__fmul_rn(dx, dx), __fmul_rn(dy, dy)),
                           __fmul_rn(dz, dz));
      valid = (sqrtf(d2) < 5.0f);
      if (valid) {
        if (p < Pc) { atomicAdd(&cntA[i], 1u); atomicAdd(&cntC[j], 1u); }
        else        { atomicAdd(&cntB[i], 1u); atomicAdd(&cntD[j], 1u); }
      }
    }
    ull bal = __ballot(valid);
    if (lane == 0) {
      if (inr) mask64[p0 >> 6] = bal;
      wrun += (unsigned)__popcll(bal);
    }
    // fused zero-fill: 2 float4 per thread per round, contiguous per block
    ll f0 = fillBase + ((ll)r << 9);
    if (f0 < T4) zp[f0] = z4;
    ll f1 = f0 + BLK;
    if (f1 < T4) zp[f1] = z4;
  }
  if (lane == 0) wcnt[wave] = wrun;
  __syncthreads();
  if (tid == 0)
    blockCount[blockIdx.x] = wcnt[0] + wcnt[1] + wcnt[2] + wcnt[3];
}

// ---------------- kernel 2: fused finisher. blocks [0,nb): invalid idx writer;
// blocks [nb, nb+N_): valid scatter for atom a = blockIdx-nb. Each block computes
// its own prefix sums from blockCount / cnt arrays (redundant, L2-hot, removes k_scan).
__global__ __launch_bounds__(BLK) void k_finish(
    const ull* __restrict__ mask64, const float* __restrict__ box,
    const int* __restrict__ shifts, int S, ll Pc, ll P, ll T, int nb,
    const unsigned* __restrict__ cntA, const unsigned* __restrict__ cntB,
    const unsigned* __restrict__ cntC, const unsigned* __restrict__ cntD,
    const unsigned* __restrict__ blockCount,
    float* __restrict__ out)
{
  __shared__ unsigned part[BLK];
  __shared__ unsigned res[8];
  __shared__ float ssv[16][3];
  __shared__ unsigned wq[4];
  int tid = threadIdx.x, lane = tid & 63, wave = tid >> 6;
  float* oi = out;
  float* oj = out + T;
  float* oo = out + 2 * T;
  float* ov = out + 5 * T;
  ull lt = (1ull << lane) - 1ull;

  if ((int)blockIdx.x < nb) {
    // ================= invalid writer =================
    int b = (int)blockIdx.x;
    unsigned mysum = 0;
    int e0 = 4 * tid;
#pragma unroll
    for (int e = 0; e < 4; ++e) { int m = e0 + e; if (m < nb) mysum += blockCount[m]; }
    part[tid] = mysum;
    for (int off = 1; off < BLK; off <<= 1) {
      __syncthreads();
      unsigned x = (tid >= off) ? part[tid - off] : 0u;
      __syncthreads();
      part[tid] += x;
    }
    __syncthreads();
    if (tid == 0) {
      int q = b >> 2;
      unsigned excl = (q > 0) ? part[q - 1] : 0u;
      for (int m = 4 * q; m < b; ++m) excl += blockCount[m];
      res[0] = excl;            // valid count before this block
      res[1] = part[BLK - 1];   // Vp = total valid pair count
    }
    // per-wave quarter: 64 mask words, one per lane
    ll qbase = (ll)b * CHUNK + (ll)wave * QUART;
    ll widx = (qbase >> 6) + lane;
    ull myword = (widx < (P >> 6)) ? mask64[widx] : ~0ull;
    unsigned ws = (unsigned)__popcll(myword);
    for (int d = 1; d < 64; d <<= 1) ws += __shfl_xor(ws, d);
    if (lane == 0) wq[wave] = ws;
    __syncthreads();
    unsigned gv = res[0];
    for (int w2 = 0; w2 < 4; ++w2) if (w2 < wave) gv += wq[w2];
    unsigned Vp = res[1], V = 2u * Vp;
    ll invDelta = P - (ll)Vp;
    unsigned vrun = gv;
    for (int k = 0; k < 64; ++k) {
      ull w64 = __shfl((long long)myword, k);
      ll p = qbase + ((ll)k << 6) + lane;
      bool invalid = !((w64 >> lane) & 1ull) && (p < P);
      if (invalid) {
        unsigned vb = vrun + (unsigned)__popcll(w64 & lt);
        ll posF = (ll)V + (p - (ll)vb);
        ll posR = posF + invDelta;
        int i, j;
        if (p < Pc) {
          decode_center(p, i, j);
        } else {
          ll q = p - Pc;
          i = (int)((q >> 10) & (N_ - 1));
          j = (int)(q & (N_ - 1));
        }
        float fi = (float)i, fj = (float)j;
        oi[posF] = fi; oj[posF] = fj;
        oi[posR] = fj; oj[posR] = fi;
      }
      vrun += (unsigned)__popcll(w64);
    }
  } else {
    // ================= valid scatter for atom a =================
    int a = (int)blockIdx.x - nb;
    if (tid < S) {
      for (int k = 0; k < 3; ++k) {
        float acc = 0.f;
        for (int m = 0; m < 3; ++m)
          acc = __fadd_rn(acc, __fmul_rn((float)shifts[3 * tid + m], box[3 * m + k]));
        ssv[tid][k] = acc;
      }
    }
    unsigned mysum = 0;
    int m0 = 4 * tid;   // 256 threads x 4 atoms = all 1024 atoms, no guard needed
#pragma unroll
    for (int e = 0; e < 4; ++e) {
      int m = m0 + e;
      mysum += cntA[m] + cntB[m] + cntC[m] + cntD[m];
    }
    part[tid] = mysum;
    for (int off = 1; off < BLK; off <<= 1) {
      __syncthreads();
      unsigned x = (tid >= off) ? part[tid - off] : 0u;
      __syncthreads();
      part[tid] += x;
    }
    __syncthreads();
    if (tid == 0) {
      int q = a >> 2;
      unsigned excl = (q > 0) ? part[q - 1] : 0u;
      for (int m = 4 * q; m < a; ++m)
        excl += cntA[m] + cntB[m] + cntC[m] + cntD[m];
      unsigned sA = excl;
      unsigned sB = sA + cntA[a];
      unsigned sC = sB + cntB[a];
      unsigned sD = sC + cntC[a];
      res[0] = sA; res[1] = sB; res[2] = sC; res[3] = sD;
    }
    __syncthreads();
    if (wave == 0) {               // A: center forward, row (a, j>a), offset = 0 (fill)
      unsigned run = res[0];
      int len = N_ - 1 - a;
      ll rb = rowstart(a);
      int steps = (len + 63) >> 6;
      for (int k = 0; k < steps; ++k) {
        int idx = (k << 6) + lane;
        bool v = false;
        if (idx < len) { ll b = rb + idx; v = (mask64[b >> 6] >> (b & 63)) & 1ull; }
        ull bal = __ballot(v);
        if (v) {
          ll pos = (ll)(run + (unsigned)__popcll(bal & lt));
          oi[pos] = (float)a; oj[pos] = (float)(a + 1 + idx); ov[pos] = 1.f;
        }
        run += (unsigned)__popcll(bal);
      }
    } else if (wave == 1) {        // B: shifted forward (s, a, j), offset = -sv[s]
      unsigned run = res[1];
      for (int s = 0; s < S; ++s) {
        ll bb = Pc + ((ll)s << 20) + ((ll)a << 10);
        float ox = -ssv[s][0], oy = -ssv[s][1], oz = -ssv[s][2];
        for (int k = 0; k < 16; ++k) {
          int j = (k << 6) + lane;
          ll b = bb + j;
          bool v = (mask64[b >> 6] >> (b & 63)) & 1ull;
          ull bal = __ballot(v);
          if (v) {
            ll pos = (ll)(run + (unsigned)__popcll(bal & lt));
            oi[pos] = (float)a; oj[pos] = (float)j; ov[pos] = 1.f;
            oo[3 * pos + 0] = ox; oo[3 * pos + 1] = oy; oo[3 * pos + 2] = oz;
          }
          run += (unsigned)__popcll(bal);
        }
      }
    } else if (wave == 2) {        // C: center reversed (i < a, a), offset = 0 (fill)
      unsigned run = res[2];
      int steps = (a + 63) >> 6;
      for (int k = 0; k < steps; ++k) {
        int i = (k << 6) + lane;
        bool v = false;
        if (i < a) { ll b = rowstart(i) + (a - i - 1); v = (mask64[b >> 6] >> (b & 63)) & 1ull; }
        ull bal = __ballot(v);
        if (v) {
          ll pos = (ll)(run + (unsigned)__popcll(bal & lt));
          oi[pos] = (float)a; oj[pos] = (float)i; ov[pos] = 1.f;
        }
        run += (unsigned)__popcll(bal);
      }
    } else {                       // D: shifted reversed (s, i, a), offset = +sv[s]
      unsigned run = res[3];
      for (int s = 0; s < S; ++s) {
        ll bb = Pc + ((ll)s << 20) + a;
        float ox = ssv[s][0], oy = ssv[s][1], oz = ssv[s][2];
        for (int k = 0; k < 16; ++k) {
          int i = (k << 6) + lane;
          ll b = bb + ((ll)i << 10);
          bool v = (mask64[b >> 6] >> (b & 63)) & 1ull;
          ull bal = __ballot(v);
          if (v) {
            ll pos = (ll)(run + (unsigned)__popcll(bal & lt));
            oi[pos] = (float)a; oj[pos] = (float)i; ov[pos] = 1.f;
            oo[3 * pos + 0] = ox; oo[3 * pos + 1] = oy; oo[3 * pos + 2] = oz;
          }
          run += (unsigned)__popcll(bal);
        }
      }
    }
  }
}

static inline unsigned char* alignup(unsigned char* p, size_t a) {
  return (unsigned char*)(((uintptr_t)p + a - 1) & ~(uintptr_t)(a - 1));
}

extern "C" void kernel_launch(void* const* d_in, const int* in_sizes, int n_in,
                              void* d_out, int out_size, void* d_ws, size_t ws_size,
                              hipStream_t stream)
{
  const float* pos = (const float*)d_in[0];
  const float* box = (const float*)d_in[1];
  const int* shifts = (const int*)d_in[2];
  int S = in_sizes[2] / 3;                       // 13
  ll Pc = (ll)N_ * (N_ - 1) / 2;                 // 523776
  ll P = Pc + (ll)S * N_ * N_;                   // 14,155,264
  ll T = 2 * P;                                  // 28,310,528
  ll T4 = T;                                     // float4 count of region [2T,6T)
  float* out = (float*)d_out;
  int nb = (int)((P + CHUNK - 1) / CHUNK);       // 864

  unsigned char* w = (unsigned char*)d_ws;
  ull* mask64 = (ull*)w;
  w += ((P + 63) / 64) * sizeof(ull);
  w = alignup(w, 256);
  unsigned* blockCount = (unsigned*)w; w += (size_t)nb * 4;
  w = alignup(w, 256);
  unsigned* cnt = (unsigned*)w;        w += (size_t)4 * N_ * 4;  // A,B,C,D contiguous
  unsigned* cntA = cnt, *cntB = cnt + N_, *cntC = cnt + 2 * N_, *cntD = cnt + 3 * N_;

  // zero only the tiny atomic counters (16 KB); out[2T,6T) zero-fill is fused
  // into k_classify (overlaps its VALU work), idx regions come from k_finish.
  hipMemsetAsync(cnt, 0, (size_t)4 * N_ * sizeof(unsigned), stream);

  k_classify<<<nb, BLK, 0, stream>>>(pos, box, shifts, S, Pc, P, T4,
                                     (float4*)(out + 2 * T),
                                     mask64, blockCount, cntA, cntB, cntC, cntD);
  k_finish<<<nb + N_, BLK, 0, stream>>>(mask64, box, shifts, S, Pc, P, T, nb,
                                        cntA, cntB, cntC, cntD, blockCount, out);
}